// Round 6
// baseline (159.373 us; speedup 1.0000x reference)
//
#include <hip/hip_runtime.h>

// HungarianMatcher cost kernel — R6 COUNTER PROBE (not an optimization).
// C[q,t] = sum_d mask[t,d]*|kp[q,d]-tgt[t,d]| + (pos-neg)[q, ids[t]]
//
// The harness's 268MB 0xAA poison fills (~40us each) occupy all rocprof
// top-5 slots, so our ~10us kernel has never shown real counters. This
// round: R5 body wrapped in a runtime rep-loop (16x, idempotent -> same
// output) with NO __restrict__ anywhere, so out-stores may alias inputs
// and the compiler must fully re-load/re-stage/re-compute each rep.
// Kernel becomes top-1 in rocprof => real VALUBusy / Occupancy / LDS
// conflict / FETCH numbers. Interpretation:
//   VALUBusy>=65% -> warm loop VALU-bound, single-shot cost is cold-start
//   VALUBusy<=35% -> latency-bound even warm -> need more waves/CU
// Next round reverts to reps=1 and acts on the diagnosis.

#define ALPHA 0.25f
#define EPS 1e-8f

constexpr int Q  = 16 * 1024;  // bs*nq
constexpr int T  = 64;
constexpr int D  = 63;
constexpr int QB = 64;         // q rows per block
constexpr int P  = 68;         // LDS pitch in floats (34 float2)
constexpr int P2 = 34;

__device__ inline float focal_cost(float x) {
  float p   = 1.0f / (1.0f + __expf(-x));
  float pos = ALPHA * (1.0f - p) * (1.0f - p) * (-__logf(p + EPS));
  float neg = (1.0f - ALPHA) * p * p * (-__logf(1.0f - p + EPS));
  return pos - neg;
}

__global__ __launch_bounds__(512) void matcher_kernel(
    const float* logits,  // [Q,2]
    const float* kp,      // [Q,63]
    const float* tgt,     // [64,63]
    const int*   ids,     // [64]
    float*       out,     // [Q,64]
    int reps)
{
  __shared__ __align__(16) float Bv[64 * P];  // [d][t]
  __shared__ __align__(16) float Bm[64 * P];  // [d][t] mask 0/1
  __shared__ float Lcc[QB * 2];               // focal cost per (q,cls)
  __shared__ int   Ids[T];

  const int tid   = threadIdx.x;
  const int qbase = blockIdx.x * QB;

  for (int rep = 0; rep < reps; ++rep) {
    // ---- stage B: tgt values + visibility mask, transposed ----
    {
      const float4* src = (const float4*)tgt;
      for (int j = tid; j < T * D / 4; j += 512) {
        float4 v = src[j];
        int i0 = 4 * j;
        float vv[4] = {v.x, v.y, v.z, v.w};
#pragma unroll
        for (int c = 0; c < 4; ++c) {
          int idx = i0 + c;
          int t = idx / D;
          int d = idx - t * D;
          Bv[d * P + t] = vv[c];
          Bm[d * P + t] = (vv[c] > 0.0f) ? 1.0f : 0.0f;
        }
      }
    }
    if (tid < QB * 2) Lcc[tid] = focal_cost(logits[qbase * 2 + tid]);
    if (tid < T) Ids[tid] = ids[tid];
    __syncthreads();

    const int qg = tid >> 5;  // 0..15 -> q = qbase + 4*qg + i
    const int tg = tid & 31;  // 0..31 -> t = 2*tg + j

    const float* r0 = kp + (qbase + qg * 4 + 0) * D;
    const float* r1 = kp + (qbase + qg * 4 + 1) * D;
    const float* r2 = kp + (qbase + qg * 4 + 2) * D;
    const float* r3 = kp + (qbase + qg * 4 + 3) * D;

    float2 acc0 = make_float2(0.f, 0.f);
    float2 acc1 = acc0, acc2 = acc0, acc3 = acc0;

    const float2* Bv2 = (const float2*)Bv;
    const float2* Bm2 = (const float2*)Bm;

#pragma unroll 7
    for (int d = 0; d < D; ++d) {
      float a0 = r0[d], a1 = r1[d], a2 = r2[d], a3 = r3[d];
      float2 bv = Bv2[d * P2 + tg];
      float2 bm = Bm2[d * P2 + tg];
      acc0.x += bm.x * fabsf(a0 - bv.x);
      acc0.y += bm.y * fabsf(a0 - bv.y);
      acc1.x += bm.x * fabsf(a1 - bv.x);
      acc1.y += bm.y * fabsf(a1 - bv.y);
      acc2.x += bm.x * fabsf(a2 - bv.x);
      acc2.y += bm.y * fabsf(a2 - bv.y);
      acc3.x += bm.x * fabsf(a3 - bv.x);
      acc3.y += bm.y * fabsf(a3 - bv.y);
    }

    // ---- epilogue ----
    const int t0 = tg * 2;
    int id0 = min(max(Ids[t0 + 0], 0), 1);
    int id1 = min(max(Ids[t0 + 1], 0), 1);

    float2 accs[4] = {acc0, acc1, acc2, acc3};
#pragma unroll
    for (int i = 0; i < 4; ++i) {
      int ql = qg * 4 + i;
      float cc[2] = {Lcc[ql * 2 + 0], Lcc[ql * 2 + 1]};
      float2 r;
      r.x = accs[i].x + cc[id0];
      r.y = accs[i].y + cc[id1];
      *(float2*)&out[(qbase + ql) * T + t0] = r;
    }
    __syncthreads();  // protect Bv/Bm restage next rep
  }
}

extern "C" void kernel_launch(void* const* d_in, const int* in_sizes, int n_in,
                              void* d_out, int out_size, void* d_ws, size_t ws_size,
                              hipStream_t stream) {
  const float* logits = (const float*)d_in[0];
  const float* kp     = (const float*)d_in[1];
  const float* tgt    = (const float*)d_in[2];
  const int*   ids    = (const int*)d_in[3];
  float* out = (float*)d_out;

  matcher_kernel<<<dim3(Q / QB), dim3(512), 0, stream>>>(logits, kp, tgt, ids, out, 16);
}

// Round 7
// 67.303 us; speedup vs baseline: 2.3680x; 2.3680x over previous
//
#include <hip/hip_runtime.h>

// HungarianMatcher cost kernel.
// C[q,t] = sum_d mask[t,d]*|kp[q,d]-tgt[t,d]| + (pos-neg)[q, ids[t]]
// Q=16384, T=64, D=63, C=2 classes.
//
// R6 probe diagnosis: warm loop ~7.2us, VALUBusy 58%, conflicts only in
// staging. Per-iter broadcast global A-loads (~8cyc ea, 256 cyc/CU-iter)
// were the wall -> R5 was VMEM-issue-bound.
// R7: wave w owns 4 q-rows, lane = t. A is wave-uniform -> s_load chunks
// (scalar pipe, zero VMEM). B: one fp32 [d][t] LDS array, ds_read_b32
// (64 consecutive dwords/wave = conflict-free); mask recomputed as bv>0
// (exact), cmp+cndmask shared across the 4 rows. 512 blocks x 512 thr
// (QB=32) -> 16 waves/CU = 4/SIMD. Walls: VALU 80 cyc/SIMD-iter,
// LDS 93 cyc/CU-iter -> ~2.5us loop.

#define ALPHA 0.25f
#define EPS 1e-8f

constexpr int Q  = 16 * 1024;  // bs*nq
constexpr int T  = 64;
constexpr int D  = 63;
constexpr int QB = 32;         // q rows per block (8 waves x 4 rows)
constexpr int P  = 66;         // LDS pitch in floats

__device__ inline float focal_cost(float x) {
  float p   = 1.0f / (1.0f + __expf(-x));
  float pos = ALPHA * (1.0f - p) * (1.0f - p) * (-__logf(p + EPS));
  float neg = (1.0f - ALPHA) * p * p * (-__logf(1.0f - p + EPS));
  return pos - neg;
}

__global__ __launch_bounds__(512) void matcher_kernel(
    const float* __restrict__ logits,  // [Q,2]
    const float* __restrict__ kp,      // [Q,63]
    const float* __restrict__ tgt,     // [64,63]
    const int*   __restrict__ ids,     // [64]
    float* __restrict__ out)           // [Q,64]
{
  __shared__ __align__(16) float Bv[D * P];  // [d][t] fp32
  __shared__ float Lcc[QB * 2];              // focal cost per (q,cls)
  __shared__ int   Ids[T];

  const int tid   = threadIdx.x;
  const int qbase = blockIdx.x * QB;

  // ---- stage B: tgt transposed [d][t]. t = tid>>3, d = 8c+i (c = tid&7).
  // Writes: banks (16c + 2i + t)%32 -> <=4-way. Reads coalesced-ish. ----
  {
    const int t = tid >> 3;
    const int c = tid & 7;
#pragma unroll
    for (int i = 0; i < 8; ++i) {
      int d = 8 * c + i;
      if (d < D) Bv[d * P + t] = tgt[t * D + d];
    }
  }
  if (tid < QB * 2) Lcc[tid] = focal_cost(logits[qbase * 2 + tid]);
  if (tid < T) Ids[tid] = ids[tid];
  __syncthreads();

  // Wave-uniform wave id -> row pointers provably uniform -> s_load.
  const int w    = __builtin_amdgcn_readfirstlane(tid) >> 6;  // 0..7
  const int lane = tid & 63;                                  // = t
  const int qrow = qbase + 4 * w;                             // first of 4 rows

  const float* __restrict__ r0 = kp + (qrow + 0) * D;
  const float* __restrict__ r1 = kp + (qrow + 1) * D;
  const float* __restrict__ r2 = kp + (qrow + 2) * D;
  const float* __restrict__ r3 = kp + (qrow + 3) * D;

  float acc0 = 0.f, acc1 = 0.f, acc2 = 0.f, acc3 = 0.f;

  // 8 chunks of 8 d (last chunk 7). A chunk = 4 uniform 8-dword loads
  // (s_load_dwordx8) into registers; inner iters: 1 ds_read_b32 + 10 VALU.
#pragma unroll
  for (int chunk = 0; chunk < 8; ++chunk) {
    const int d0 = chunk * 8;
    const int nd = (chunk == 7) ? 7 : 8;
    float a0[8], a1[8], a2[8], a3[8];
#pragma unroll
    for (int j = 0; j < 8; ++j) {
      if (j < nd) {
        a0[j] = r0[d0 + j];
        a1[j] = r1[d0 + j];
        a2[j] = r2[d0 + j];
        a3[j] = r3[d0 + j];
      }
    }
#pragma unroll
    for (int j = 0; j < 8; ++j) {
      if (j < nd) {
        float bv = Bv[(d0 + j) * P + lane];
        float bm = bv > 0.0f ? 1.0f : 0.0f;
        acc0 += bm * fabsf(a0[j] - bv);
        acc1 += bm * fabsf(a1[j] - bv);
        acc2 += bm * fabsf(a2[j] - bv);
        acc3 += bm * fabsf(a3[j] - bv);
      }
    }
  }

  // ---- epilogue: add focal cost, coalesced dword stores (64/row/wave) ----
  const int id = min(max(Ids[lane], 0), 1);  // all-broadcast-ish LDS reads
  const int ql = 4 * w;                      // local q of row 0
  out[(qrow + 0) * T + lane] = acc0 + Lcc[(ql + 0) * 2 + id];
  out[(qrow + 1) * T + lane] = acc1 + Lcc[(ql + 1) * 2 + id];
  out[(qrow + 2) * T + lane] = acc2 + Lcc[(ql + 2) * 2 + id];
  out[(qrow + 3) * T + lane] = acc3 + Lcc[(ql + 3) * 2 + id];
}

extern "C" void kernel_launch(void* const* d_in, const int* in_sizes, int n_in,
                              void* d_out, int out_size, void* d_ws, size_t ws_size,
                              hipStream_t stream) {
  const float* logits = (const float*)d_in[0];
  const float* kp     = (const float*)d_in[1];
  const float* tgt    = (const float*)d_in[2];
  const int*   ids    = (const int*)d_in[3];
  float* out = (float*)d_out;

  matcher_kernel<<<dim3(Q / QB), dim3(512), 0, stream>>>(logits, kp, tgt, ids, out);
}